// Round 2
// baseline (67802.509 us; speedup 1.0000x reference)
//
#include <hip/hip_runtime.h>
#include <stdint.h>

typedef unsigned long long u64;

#define SLEN 8192
#define NBLK 128

// ws layout (u64 units): all rings depth-2, tagged (step<<32 | f32 bits)
//   h0 ring [2][1024] @ 0
//   h1 ring [2][1024] @ 2048
//   pp ring [2][1024] @ 4096   (per-wave partial of w_ffn·h1, no b_ffn)
#define H0_OFF 0
#define H1_OFF 2048
#define PP_OFF 4096
#define WS_U64 6144

__device__ __forceinline__ u64 ld_agent(const u64* p) {
  return __hip_atomic_load((u64*)p, __ATOMIC_RELAXED, __HIP_MEMORY_SCOPE_AGENT);
}
__device__ __forceinline__ void pub(u64* p, float f, unsigned tag) {
  u64 v = ((u64)tag << 32) | (u64)__float_as_uint(f);
  __hip_atomic_store(p, v, __ATOMIC_RELAXED, __HIP_MEMORY_SCOPE_AGENT);
}
// finish a previously-issued poll load: spin until tag matches
__device__ __forceinline__ float finish(const u64* p, u64 v, unsigned tag) {
  while ((unsigned)(v >> 32) != tag) {
    __builtin_amdgcn_s_sleep(1);
    v = ld_agent(p);
  }
  return __uint_as_float((unsigned)v);
}
__device__ __forceinline__ float sigm(float v) { return 1.f / (1.f + expf(-v)); }
__device__ __forceinline__ float tanh_f(float v) {
  float e = expf(-2.f * fabsf(v));
  return copysignf((1.f - e) / (1.f + e), v);
}

// padded LDS layout: 64 chunks of 16 floats, chunk stride 20 floats (80 B)
__device__ __forceinline__ int lds_idx(int k) { return (k >> 4) * 20 + (k & 15); }

__device__ __forceinline__ void mv4(float acc[4], const float4 w[4][4],
                                    const float* lds_base) {
  const float4* hv = reinterpret_cast<const float4*>(lds_base);
#pragma unroll
  for (int u = 0; u < 4; ++u) {
    float4 h = hv[u];
#pragma unroll
    for (int g = 0; g < 4; ++g)
      acc[g] += w[g][u].x * h.x + w[g][u].y * h.y + w[g][u].z * h.z + w[g][u].w * h.w;
  }
}
#define BUTTERFLY4(acc)                                        \
  _Pragma("unroll") for (int off = 1; off < 64; off <<= 1) {   \
    _Pragma("unroll") for (int g = 0; g < 4; ++g)              \
        acc[g] += __shfl_xor(acc[g], off, 64);                 \
  }

__global__ __launch_bounds__(512, 2) void lstm_fused(
    const float* __restrict__ x, const int* __restrict__ mask,
    const float* __restrict__ feat, const int* __restrict__ tfp,
    const float* __restrict__ w_ih0, const float* __restrict__ w_hh0,
    const float* __restrict__ b_ih0, const float* __restrict__ b_hh0,
    const float* __restrict__ w_ih1, const float* __restrict__ w_hh1,
    const float* __restrict__ b_ih1, const float* __restrict__ b_hh1,
    const float* __restrict__ w_ffn, const float* __restrict__ b_ffn,
    float* __restrict__ out, u64* __restrict__ ws)
{
  u64* h0r = ws + H0_OFF;
  u64* h1r = ws + H1_OFF;
  u64* ppr = ws + PP_OFF;
  const int tid = threadIdx.x, lane = tid & 63, wv = tid >> 6;
  const int blk = blockIdx.x;
  const int m = blk * 8 + wv;       // owned hidden unit (same for both layers)
  const int k0 = tid * 2;
  const bool tf1 = (*tfp) >= 1;

  __shared__ __align__(16) float lh0[2][1280];
  __shared__ __align__(16) float lh1[1280];
  __shared__ float lyp[512];
  __shared__ float lys;

  // ---- weights into VGPRs: 3 matrices x 4 gates x 16 floats = 192 VGPR ----
  float4 wh0[4][4], wi1[4][4], wh1[4][4];
#pragma unroll
  for (int g = 0; g < 4; ++g) {
    const size_t row = (size_t)(1024 * g + m);
    const float4* s0 = reinterpret_cast<const float4*>(w_hh0 + row * 1024 + lane * 16);
    const float4* s1 = reinterpret_cast<const float4*>(w_ih1 + row * 1024 + lane * 16);
    const float4* s2 = reinterpret_cast<const float4*>(w_hh1 + row * 1024 + lane * 16);
#pragma unroll
    for (int u = 0; u < 4; ++u) { wh0[g][u] = s0[u]; wi1[g][u] = s1[u]; wh1[g][u] = s2[u]; }
  }
  float wf[4], bb[4];
#pragma unroll
  for (int g = 0; g < 4; ++g) {
    const int row = 1024 * g + m;
    wf[g] = (lane < 16) ? w_ih0[row * 16 + lane]
          : (lane == 16 ? (b_ih0[row] + b_hh0[row]) : 0.f);
    bb[g] = (lane == 16) ? (b_ih1[row] + b_hh1[row]) : 0.f;
  }
  const float wffn = w_ffn[m];
  const float bf = b_ffn[0];
  float c0 = 0.f, c1 = 0.f;

  for (int t = 0; t < SLEN; ++t) {
    const bool use_x = (t == 0) || (tf1 && (mask[t] != 0));
    const bool needy = (t > 0) && !use_x;

    // ---------- phase B: layer-0 matvec (y-poll overlapped) ----------
    u64* pp0 = &ppr[((t - 1) & 1) * 1024 + k0];
    u64 vp0, vp1;
    if (needy) { vp0 = ld_agent(pp0); vp1 = ld_agent(pp0 + 1); }  // issue early

    float base_in = (lane == 0) ? (use_x ? x[t] : 0.f)
                  : (lane < 16) ? feat[t * 15 + lane - 1]
                  : (lane == 16) ? 1.f : 0.f;
    float acc[4];
#pragma unroll
    for (int g = 0; g < 4; ++g) acc[g] = wf[g] * base_in;
    if (t > 0) mv4(acc, wh0, &lh0[(t - 1) & 1][lane * 20]);
    BUTTERFLY4(acc);

    if (needy) {
      float p0 = finish(pp0, vp0, (unsigned)(t - 1));
      float p1 = finish(pp0 + 1, vp1, (unsigned)(t - 1));
      lyp[tid] = p0 + p1;
      __syncthreads();
      if (wv == 0) {
        float s = 0.f;
#pragma unroll
        for (int j = 0; j < 8; ++j) s += lyp[lane + 64 * j];
#pragma unroll
        for (int off = 1; off < 64; off <<= 1) s += __shfl_xor(s, off, 64);
        if (lane == 0) lys = s + bf;
      }
      __syncthreads();
    }
    if (lane == 0) {
      if (needy) {
        float y = lys;
#pragma unroll
        for (int g = 0; g < 4; ++g) acc[g] += y * wf[g];  // lane0 wf == w_ih0[:,0]
      }
      float ii = sigm(acc[0]), ff = sigm(acc[1]);
      float gg = tanh_f(acc[2]), oo = sigm(acc[3]);
      c0 = ff * c0 + ii * gg;
      float h = oo * tanh_f(c0);
      pub(&h0r[(t & 1) * 1024 + m], h, (unsigned)t);
    }

    // ---------- phase C: stage h0[t] (+ h1[t-1], + parts for blk0) ----------
    u64* q0 = &h0r[(t & 1) * 1024 + k0];
    u64 w0 = ld_agent(q0), w1 = ld_agent(q0 + 1);       // issue before other waits
    if (t > 0) {
      u64* r0 = &h1r[((t - 1) & 1) * 1024 + k0];
      u64 u0 = ld_agent(r0), u1 = ld_agent(r0 + 1);
      float a = finish(r0, u0, (unsigned)(t - 1));
      float b = finish(r0 + 1, u1, (unsigned)(t - 1));
      *reinterpret_cast<float2*>(&lh1[lds_idx(k0)]) = make_float2(a, b);
      if (blk == 0) {   // block 0 always consumes parts (for out[t-1])
        u64* s0 = &ppr[((t - 1) & 1) * 1024 + k0];
        u64 z0 = ld_agent(s0), z1 = ld_agent(s0 + 1);
        float pa = finish(s0, z0, (unsigned)(t - 1));
        float pb = finish(s0 + 1, z1, (unsigned)(t - 1));
        lyp[tid] = pa + pb;
      }
    }
    {
      float a = finish(q0, w0, (unsigned)t);
      float b = finish(q0 + 1, w1, (unsigned)t);
      *reinterpret_cast<float2*>(&lh0[t & 1][lds_idx(k0)]) = make_float2(a, b);
    }
    __syncthreads();

    // ---------- phase D: layer-1 matvec ----------
    float acc1[4];
#pragma unroll
    for (int g = 0; g < 4; ++g) acc1[g] = bb[g];
    if (t > 0) mv4(acc1, wh1, &lh1[lane * 20]);
    mv4(acc1, wi1, &lh0[t & 1][lane * 20]);
    BUTTERFLY4(acc1);

    if (blk == 0 && t > 0 && wv == 0) {   // write out[t-1] (deterministic order)
      float s = 0.f;
#pragma unroll
      for (int j = 0; j < 8; ++j) s += lyp[lane + 64 * j];
#pragma unroll
      for (int off = 1; off < 64; off <<= 1) s += __shfl_xor(s, off, 64);
      if (lane == 0) out[t - 1] = s + bf;
    }
    if (lane == 0) {
      float ii = sigm(acc1[0]), ff = sigm(acc1[1]);
      float gg = tanh_f(acc1[2]), oo = sigm(acc1[3]);
      c1 = ff * c1 + ii * gg;
      float h = oo * tanh_f(c1);
      pub(&h1r[(t & 1) * 1024 + m], h, (unsigned)t);
      pub(&ppr[(t & 1) * 1024 + m], wffn * h, (unsigned)t);
    }
    __syncthreads();
  }

  // ---------- tail: out[SLEN-1] ----------
  if (blk == 0) {
    u64* s0 = &ppr[((SLEN - 1) & 1) * 1024 + k0];
    u64 z0 = ld_agent(s0), z1 = ld_agent(s0 + 1);
    float pa = finish(s0, z0, (unsigned)(SLEN - 1));
    float pb = finish(s0 + 1, z1, (unsigned)(SLEN - 1));
    lyp[tid] = pa + pb;
    __syncthreads();
    if (wv == 0) {
      float s = 0.f;
#pragma unroll
      for (int j = 0; j < 8; ++j) s += lyp[lane + 64 * j];
#pragma unroll
      for (int off = 1; off < 64; off <<= 1) s += __shfl_xor(s, off, 64);
      if (lane == 0) out[SLEN - 1] = s + bf;
    }
  }
}

extern "C" void kernel_launch(void* const* d_in, const int* in_sizes, int n_in,
                              void* d_out, int out_size, void* d_ws, size_t ws_size,
                              hipStream_t stream) {
  (void)in_sizes; (void)n_in; (void)out_size; (void)ws_size;
  const float* x      = (const float*)d_in[0];
  const int*   mask   = (const int*)  d_in[1];
  const float* feat   = (const float*)d_in[2];
  const int*   tfp    = (const int*)  d_in[3];
  const float* w_ih0  = (const float*)d_in[4];
  const float* w_hh0  = (const float*)d_in[5];
  const float* b_ih0  = (const float*)d_in[6];
  const float* b_hh0  = (const float*)d_in[7];
  const float* w_ih1  = (const float*)d_in[8];
  const float* w_hh1  = (const float*)d_in[9];
  const float* b_ih1  = (const float*)d_in[10];
  const float* b_hh1  = (const float*)d_in[11];
  const float* w_ffn  = (const float*)d_in[12];
  const float* b_ffn  = (const float*)d_in[13];
  float* out = (float*)d_out;
  u64*   ws  = (u64*)d_ws;

  // invalidate ring tags (0xFFFFFFFF never equals a step index)
  hipMemsetAsync(d_ws, 0xFF, (size_t)WS_U64 * sizeof(u64), stream);

  lstm_fused<<<dim3(NBLK), dim3(512), 0, stream>>>(
      x, mask, feat, tfp, w_ih0, w_hh0, b_ih0, b_hh0,
      w_ih1, w_hh1, b_ih1, b_hh1, w_ffn, b_ffn, out, ws);
}

// Round 3
// 57031.378 us; speedup vs baseline: 1.1889x; 1.1889x over previous
//
#include <hip/hip_runtime.h>
#include <stdint.h>

typedef float f32x4 __attribute__((ext_vector_type(4)));

#define SLEN 8192
#define NBLK 128

// Global chunk rings in d_ws: 2 vectors (h0,h1) x 2 parities x 128 slots x 64B.
// Slot p, chunk c (c=0,1,2) at byte p*64 + c*16: [f0, f1, f2, tag]
//   c=0: h[p*8+0..2]   c=1: h[p*8+3..5]   c=2: h[p*8+6], h[p*8+7], ypart
// Published/consumed as single 16B transactions with sc0 sc1 (coherence point =
// Infinity Cache), so each chunk is self-validating via its embedded tag.
#define PAR_BYTES (128 * 64)          // 8192 per parity
#define H1_BYTE   (2 * PAR_BYTES)     // h0 at 0, h1 at 16384
#define WS_BYTES  (4 * PAR_BYTES)     // 32768

__device__ __forceinline__ void st_chunk(void* addr, f32x4 v) {
  asm volatile("global_store_dwordx4 %0, %1, off sc0 sc1"
               :: "v"(addr), "v"(v) : "memory");
}
__device__ __forceinline__ f32x4 ld_chunk(const void* addr) {
  f32x4 v;
  asm volatile("global_load_dwordx4 %0, %1, off sc0 sc1\n\ts_waitcnt vmcnt(0)"
               : "=v"(v) : "v"(addr) : "memory");
  return v;
}
// retry until the tag word (element 3) equals 'tag'
__device__ __forceinline__ f32x4 poll_chunk(const void* addr, unsigned tag) {
  f32x4 v = ld_chunk(addr);
  while (__float_as_uint(v.w) != tag) {
    __builtin_amdgcn_s_sleep(1);
    v = ld_chunk(addr);
  }
  return v;
}

__device__ __forceinline__ float sigm(float v) { return 1.f / (1.f + expf(-v)); }
__device__ __forceinline__ float tanh_f(float v) {
  float e = expf(-2.f * fabsf(v));
  return copysignf((1.f - e) / (1.f + e), v);
}

// padded LDS layout: 64 chunks of 16 floats, chunk stride 20 floats (80 B)
__device__ __forceinline__ int lds_idx(int k) { return (k >> 4) * 20 + (k & 15); }

__device__ __forceinline__ void mv4(float acc[4], const float4 w[4][4],
                                    const float* lds_base) {
  const float4* hv = reinterpret_cast<const float4*>(lds_base);
#pragma unroll
  for (int u = 0; u < 4; ++u) {
    float4 h = hv[u];
#pragma unroll
    for (int g = 0; g < 4; ++g)
      acc[g] += w[g][u].x * h.x + w[g][u].y * h.y + w[g][u].z * h.z + w[g][u].w * h.w;
  }
}
#define BUTTERFLY4(acc)                                        \
  _Pragma("unroll") for (int off = 1; off < 64; off <<= 1) {   \
    _Pragma("unroll") for (int g = 0; g < 4; ++g)              \
        acc[g] += __shfl_xor(acc[g], off, 64);                 \
  }

__global__ __launch_bounds__(512, 1) void lstm_fused(
    const float* __restrict__ x, const int* __restrict__ mask,
    const float* __restrict__ feat, const int* __restrict__ tfp,
    const float* __restrict__ w_ih0, const float* __restrict__ w_hh0,
    const float* __restrict__ b_ih0, const float* __restrict__ b_hh0,
    const float* __restrict__ w_ih1, const float* __restrict__ w_hh1,
    const float* __restrict__ b_ih1, const float* __restrict__ b_hh1,
    const float* __restrict__ w_ffn, const float* __restrict__ b_ffn,
    float* __restrict__ out, char* __restrict__ ws)
{
  char* h0ring = ws;
  char* h1ring = ws + H1_BYTE;
  const int tid = threadIdx.x, lane = tid & 63, wv = tid >> 6;
  const int blk = blockIdx.x;
  const int m = blk * 8 + wv;          // owned hidden unit (both layers)
  const bool tf1 = (*tfp) >= 1;

  // staging-thread constants (threads 0..383 move chunks -> LDS)
  const int sp = tid / 3, sc = tid - sp * 3;       // slot, chunk
  const int hb = sp * 8 + sc * 3;                  // first h index in chunk
  const int l0 = lds_idx(hb), l1 = lds_idx(hb + 1), l2 = lds_idx(hb + 2);
  const int slot_byte = sp * 64 + sc * 16;
  const bool stager = tid < 384;

  __shared__ __align__(16) float lh0[1280];
  __shared__ __align__(16) float lh1[1280];
  __shared__ float lds_h[8];
  __shared__ float lds_yp[8];
  __shared__ float lyp[128];

  // ---- weights into VGPRs: 3 matrices x 4 gates x 4 float4 = 192 VGPR ----
  float4 wh0[4][4], wi1[4][4], wh1[4][4];
#pragma unroll
  for (int g = 0; g < 4; ++g) {
    const size_t row = (size_t)(1024 * g + m);
    const float4* s0 = reinterpret_cast<const float4*>(w_hh0 + row * 1024 + lane * 16);
    const float4* s1 = reinterpret_cast<const float4*>(w_ih1 + row * 1024 + lane * 16);
    const float4* s2 = reinterpret_cast<const float4*>(w_hh1 + row * 1024 + lane * 16);
#pragma unroll
    for (int u = 0; u < 4; ++u) { wh0[g][u] = s0[u]; wi1[g][u] = s1[u]; wh1[g][u] = s2[u]; }
  }
  float wf[4], bb[4];
#pragma unroll
  for (int g = 0; g < 4; ++g) {
    const int row = 1024 * g + m;
    wf[g] = (lane < 16) ? w_ih0[row * 16 + lane]
          : (lane == 16 ? (b_ih0[row] + b_hh0[row]) : 0.f);
    bb[g] = (lane == 16) ? (b_ih1[row] + b_hh1[row]) : 0.f;
  }
  const float wffn = w_ffn[m];
  const float bf = b_ffn[0];
  float c0 = 0.f, c1 = 0.f;

  for (int t = 0; t < SLEN; ++t) {
    const bool use_x = (t == 0) || (tf1 && (mask[t] != 0));
    const bool needy = (t > 0) && !use_x;

    // ---------- phase A: stage h1[t-1] chunks -> lh1 (+ yparts -> lyp) ----------
    if (t > 0 && stager) {
      const void* a = h1ring + ((t - 1) & 1) * PAR_BYTES + slot_byte;
      f32x4 v = poll_chunk(a, (unsigned)(t - 1));
      if (sc < 2) {
        lh1[l0] = v.x; lh1[l1] = v.y; lh1[l2] = v.z;
      } else {
        lh1[l0] = v.x; lh1[l1] = v.y; lyp[sp] = v.z;
      }
    }
    __syncthreads();

    // y[t-1]: free local reduce over the 128 cached yparts (fixed order)
    float yv = 0.f;
    if ((t > 0) && (needy || (blk == 0 && wv == 0))) {
      float s = lyp[lane * 2] + lyp[lane * 2 + 1];
#pragma unroll
      for (int off = 1; off < 64; off <<= 1) s += __shfl_xor(s, off, 64);
      yv = s + bf;
    }

    // ---------- phase B: layer-0 matvec, publish h0[t] ----------
    float base_in = (lane == 0) ? (use_x ? x[t] : 0.f)
                  : (lane < 16) ? feat[t * 15 + lane - 1]
                  : (lane == 16) ? 1.f : 0.f;
    float acc[4];
#pragma unroll
    for (int g = 0; g < 4; ++g) acc[g] = wf[g] * base_in;
    if (t > 0) mv4(acc, wh0, &lh0[lane * 20]);
    BUTTERFLY4(acc);

    if (blk == 0 && wv == 0 && lane == 0 && t > 0) out[t - 1] = yv;
    if (lane == 0) {
      if (needy) {
#pragma unroll
        for (int g = 0; g < 4; ++g) acc[g] += yv * wf[g];  // lane0 wf == w_ih0[:,0]
      }
      float ii = sigm(acc[0]), ff = sigm(acc[1]);
      float gg = tanh_f(acc[2]), oo = sigm(acc[3]);
      c0 = ff * c0 + ii * gg;
      float h = oo * tanh_f(c0);
      lds_h[wv] = h; lds_yp[wv] = 0.f;
    }
    __syncthreads();
    if (tid < 3) {
      const int b = tid * 3;
      f32x4 v;
      v.x = lds_h[b];
      v.y = lds_h[(b + 1) & 7];
      v.z = (tid == 2) ? (((lds_yp[0] + lds_yp[1]) + (lds_yp[2] + lds_yp[3])) +
                          ((lds_yp[4] + lds_yp[5]) + (lds_yp[6] + lds_yp[7])))
                       : lds_h[b + 2];
      v.w = __uint_as_float((unsigned)t);
      st_chunk(h0ring + (t & 1) * PAR_BYTES + blk * 64 + tid * 16, v);
    }

    // ---------- phase C: stage h0[t] chunks -> lh0 ----------
    if (stager) {
      const void* a = h0ring + (t & 1) * PAR_BYTES + slot_byte;
      f32x4 v = poll_chunk(a, (unsigned)t);
      if (sc < 2) { lh0[l0] = v.x; lh0[l1] = v.y; lh0[l2] = v.z; }
      else        { lh0[l0] = v.x; lh0[l1] = v.y; }
    }
    __syncthreads();

    // ---------- phase D: layer-1 matvec, publish h1[t] (+ypart) ----------
    float acc1[4];
#pragma unroll
    for (int g = 0; g < 4; ++g) acc1[g] = bb[g];
    mv4(acc1, wi1, &lh0[lane * 20]);
    if (t > 0) mv4(acc1, wh1, &lh1[lane * 20]);
    BUTTERFLY4(acc1);

    if (lane == 0) {
      float ii = sigm(acc1[0]), ff = sigm(acc1[1]);
      float gg = tanh_f(acc1[2]), oo = sigm(acc1[3]);
      c1 = ff * c1 + ii * gg;
      float h = oo * tanh_f(c1);
      lds_h[wv] = h; lds_yp[wv] = wffn * h;
    }
    __syncthreads();
    if (tid < 3) {
      const int b = tid * 3;
      f32x4 v;
      v.x = lds_h[b];
      v.y = lds_h[(b + 1) & 7];
      v.z = (tid == 2) ? (((lds_yp[0] + lds_yp[1]) + (lds_yp[2] + lds_yp[3])) +
                          ((lds_yp[4] + lds_yp[5]) + (lds_yp[6] + lds_yp[7])))
                       : lds_h[b + 2];
      v.w = __uint_as_float((unsigned)t);
      st_chunk(h1ring + (t & 1) * PAR_BYTES + blk * 64 + tid * 16, v);
    }
  }

  // ---------- tail: out[SLEN-1] ----------
  if (blk == 0) {
    if (tid < 128) {
      const void* a = h1ring + ((SLEN - 1) & 1) * PAR_BYTES + tid * 64 + 32;
      f32x4 v = poll_chunk(a, (unsigned)(SLEN - 1));
      lyp[tid] = v.z;
    }
    __syncthreads();
    if (wv == 0) {
      float s = lyp[lane * 2] + lyp[lane * 2 + 1];
#pragma unroll
      for (int off = 1; off < 64; off <<= 1) s += __shfl_xor(s, off, 64);
      if (lane == 0) out[SLEN - 1] = s + bf;
    }
  }
}

extern "C" void kernel_launch(void* const* d_in, const int* in_sizes, int n_in,
                              void* d_out, int out_size, void* d_ws, size_t ws_size,
                              hipStream_t stream) {
  (void)in_sizes; (void)n_in; (void)out_size; (void)ws_size;
  const float* x      = (const float*)d_in[0];
  const int*   mask   = (const int*)  d_in[1];
  const float* feat   = (const float*)d_in[2];
  const int*   tfp    = (const int*)  d_in[3];
  const float* w_ih0  = (const float*)d_in[4];
  const float* w_hh0  = (const float*)d_in[5];
  const float* b_ih0  = (const float*)d_in[6];
  const float* b_hh0  = (const float*)d_in[7];
  const float* w_ih1  = (const float*)d_in[8];
  const float* w_hh1  = (const float*)d_in[9];
  const float* b_ih1  = (const float*)d_in[10];
  const float* b_hh1  = (const float*)d_in[11];
  const float* w_ffn  = (const float*)d_in[12];
  const float* b_ffn  = (const float*)d_in[13];
  float* out = (float*)d_out;
  char*  ws  = (char*)d_ws;

  // invalidate chunk tags (0xFFFFFFFF never equals a step index)
  hipMemsetAsync(d_ws, 0xFF, (size_t)WS_BYTES, stream);

  lstm_fused<<<dim3(NBLK), dim3(512), 0, stream>>>(
      x, mask, feat, tfp, w_ih0, w_hh0, b_ih0, b_hh0,
      w_ih1, w_hh1, b_ih1, b_hh1, w_ffn, b_ffn, out, ws);
}

// Round 4
// 53410.309 us; speedup vs baseline: 1.2695x; 1.0678x over previous
//
#include <hip/hip_runtime.h>
#include <stdint.h>

typedef float f32x4 __attribute__((ext_vector_type(4)));

#define SLEN 8192
#define NBLK 256

// rings: h1 at byte 0, h0 at 16384. Each: 2 parities x 256 CUs x 2 chunks x 16B.
// CU j, chunk0 = {h[4j],h[4j+1],h[4j+2],tag}, chunk1 = {h[4j+3], ypsum_j, 0, tag}
#define RING_PAR 8192
#define H0_OFF   16384
#define WS_BYTES 32768

__device__ __forceinline__ void st_chunk(void* addr, f32x4 v) {
  asm volatile("global_store_dwordx4 %0, %1, off sc0 sc1"
               :: "v"(addr), "v"(v) : "memory");
}
__device__ __forceinline__ void ld2(const void* a, f32x4& v0, f32x4& v1) {
  asm volatile("global_load_dwordx4 %0, %2, off sc0 sc1\n\t"
               "global_load_dwordx4 %1, %2, off offset:16 sc0 sc1\n\t"
               "s_waitcnt vmcnt(0)"
               : "=v"(v0), "=v"(v1) : "v"(a) : "memory");
}
// batched poll of a 32B (2-chunk) slot; both chunks must carry 'tag'
__device__ __forceinline__ void poll2(const void* a, unsigned tag, f32x4& v0, f32x4& v1) {
  ld2(a, v0, v1);
  while (__float_as_uint(v0.w) != tag || __float_as_uint(v1.w) != tag) {
    __builtin_amdgcn_s_sleep(2);
    ld2(a, v0, v1);
  }
}

__device__ __forceinline__ float sigm(float v) { return 1.f / (1.f + expf(-v)); }
__device__ __forceinline__ float tanh_f(float v) {
  float e = expf(-2.f * fabsf(v));
  return copysignf((1.f - e) / (1.f + e), v);
}
__device__ __forceinline__ float lstm_h(float a0, float a1, float a2, float a3, float& c) {
  float ii = sigm(a0), ff = sigm(a1), gg = tanh_f(a2), oo = sigm(a3);
  c = ff * c + ii * gg;
  return oo * tanh_f(c);
}

// wave64 sum via DPP (row_shr 1,2,4,8 then bcast15/31); total lands in lane 63
__device__ __forceinline__ float dpp_red(float x) {
  x += __int_as_float(__builtin_amdgcn_update_dpp(0, __float_as_int(x), 0x111, 0xf, 0xf, true));
  x += __int_as_float(__builtin_amdgcn_update_dpp(0, __float_as_int(x), 0x112, 0xf, 0xf, true));
  x += __int_as_float(__builtin_amdgcn_update_dpp(0, __float_as_int(x), 0x114, 0xf, 0xf, true));
  x += __int_as_float(__builtin_amdgcn_update_dpp(0, __float_as_int(x), 0x118, 0xf, 0xf, true));
  x += __int_as_float(__builtin_amdgcn_update_dpp(0, __float_as_int(x), 0x142, 0xa, 0xf, true));
  x += __int_as_float(__builtin_amdgcn_update_dpp(0, __float_as_int(x), 0x143, 0xc, 0xf, true));
  return x;
}

__device__ __forceinline__ float dot4(f32x4 a, f32x4 b) {
  return a.x * b.x + a.y * b.y + a.z * b.z + a.w * b.w;
}
// padded hidden-vector layout: chunk stride 20 floats (80B) -> conflict-free b128
__device__ __forceinline__ int lds_idx4(int j) { return (j >> 2) * 20 + (j & 3) * 4; }

__global__ __launch_bounds__(512, 2) void lstm_fused(
    const float* __restrict__ x, const int* __restrict__ mask,
    const float* __restrict__ feat, const int* __restrict__ tfp,
    const float* __restrict__ w_ih0, const float* __restrict__ w_hh0,
    const float* __restrict__ b_ih0, const float* __restrict__ b_hh0,
    const float* __restrict__ w_ih1, const float* __restrict__ w_hh1,
    const float* __restrict__ b_ih1, const float* __restrict__ b_hh1,
    const float* __restrict__ w_ffn, const float* __restrict__ b_ffn,
    float* __restrict__ out, char* __restrict__ ws)
{
  char* h1ring = ws;
  char* h0ring = ws + H0_OFF;
  const int tid = threadIdx.x, lane = tid & 63, wv = tid >> 6;
  const int blk = blockIdx.x;
  const int u = wv & 3;                 // unit within CU
  const int m = blk * 4 + u;            // owned global hidden unit
  const bool L1w = wv < 4;              // waves 0-3: layer-1 ; waves 4-7: layer-0

  __shared__ __align__(16) float wh1_lds[16 * 1280];   // 80 KB, pad-20 chunks
  __shared__ __align__(16) float lh0[1280];            // h0[t-1] -> h0[t]
  __shared__ __align__(16) float lh1[2][1280];         // h1 double-buffer by parity
  __shared__ float lyp[256];
  __shared__ float g1h[4], g1yp[4], g0h[4];
  __shared__ float lys;

  // ---- per-role weight matrix (union: 64 VGPRs total) ----
  f32x4 W[4][4];
  {
    const float* Wsrc = L1w ? w_ih1 : w_hh0;
#pragma unroll
    for (int g = 0; g < 4; ++g) {
      const f32x4* s = reinterpret_cast<const f32x4*>(
          Wsrc + (size_t)(1024 * g + m) * 1024 + lane * 16);
#pragma unroll
      for (int q = 0; q < 4; ++q) W[g][q] = s[q];
    }
  }
  float wA[4], wB[4];
#pragma unroll
  for (int g = 0; g < 4; ++g) {
    const int r = 1024 * g + m;
    if (L1w) {
      wA[g] = (lane == 16) ? (b_ih1[r] + b_hh1[r]) : 0.f;   // layer-1 bias slot
      wB[g] = 0.f;
    } else {
      wA[g] = (lane < 16) ? w_ih0[r * 16 + lane]
            : (lane == 16 ? (b_ih0[r] + b_hh0[r]) : 0.f);
      wB[g] = w_ih0[r * 16];                                 // scalar-input column
    }
  }
  const float wffn = w_ffn[m];
  const float bf = b_ffn[0];
  float cc = 0.f;                       // c1 on L1 lane63, c0 on L0 lane63
  float ap[4] = {0.f, 0.f, 0.f, 0.f};   // L1: bb + wh1*h1[t-2] prefetch

  // ---- stage w_hh1 into LDS (pad-20 layout) ----
  for (int ch = tid; ch < 1024; ch += 512) {
    const int r = ch >> 6, kc = ch & 63;
    const int grow = 1024 * (r & 3) + blk * 4 + (r >> 2);
    const f32x4* src = reinterpret_cast<const f32x4*>(
        w_hh1 + (size_t)grow * 1024 + kc * 16);
    f32x4* dst = reinterpret_cast<f32x4*>(&wh1_lds[r * 1280 + kc * 20]);
    dst[0] = src[0]; dst[1] = src[1]; dst[2] = src[2]; dst[3] = src[3];
  }
  __syncthreads();

  const bool tf1 = (*tfp) >= 1;

  for (int t = 0; t < SLEN; ++t) {
    const bool use_x = (t == 0) || (tf1 && mask[t] != 0);
    const bool needy = (t > 0) && !use_x;
    float acc0[4];

    // issue L0 per-step input loads early (overlap S1 region)
    float base = 0.f;
    if (!L1w) {
      base = (lane == 0) ? (use_x ? x[t] : 0.f)
           : (lane < 16) ? feat[t * 15 + lane - 1]
           : (lane == 16) ? 1.f : 0.f;
    }

    // ---- step1: L1 computes h1[t-1] = gates(ap + wi1*h0[t-1]) ----
    if (L1w && t > 0) {
      const f32x4* hv = reinterpret_cast<const f32x4*>(&lh0[lane * 20]);
      f32x4 h0v = hv[0], h1v = hv[1], h2v = hv[2], h3v = hv[3];
      float a[4];
#pragma unroll
      for (int g = 0; g < 4; ++g)
        a[g] = ap[g] + dot4(W[g][0], h0v) + dot4(W[g][1], h1v) +
                        dot4(W[g][2], h2v) + dot4(W[g][3], h3v);
#pragma unroll
      for (int g = 0; g < 4; ++g) a[g] = dpp_red(a[g]);
      if (lane == 63) {
        float h = lstm_h(a[0], a[1], a[2], a[3], cc);
        g1h[u] = h; g1yp[u] = wffn * h;
      }
    }
    __syncthreads();  // S1

    // ---- step2: pub h1[t-1] ; L0 matvec ; L1 polls h1[t-1] ----
    if (t > 0 && tid < 2) {
      f32x4 v;
      if (tid == 0) { v.x = g1h[0]; v.y = g1h[1]; v.z = g1h[2]; }
      else { v.x = g1h[3]; v.y = (g1yp[0] + g1yp[1]) + (g1yp[2] + g1yp[3]); v.z = 0.f; }
      v.w = __uint_as_float((unsigned)(t - 1));
      st_chunk(h1ring + ((t - 1) & 1) * RING_PAR + blk * 32 + tid * 16, v);
    }
    if (!L1w) {
#pragma unroll
      for (int g = 0; g < 4; ++g) acc0[g] = wA[g] * base;
      if (t > 0) {
        const f32x4* hv = reinterpret_cast<const f32x4*>(&lh0[lane * 20]);
        f32x4 h0v = hv[0], h1v = hv[1], h2v = hv[2], h3v = hv[3];
#pragma unroll
        for (int g = 0; g < 4; ++g)
          acc0[g] += dot4(W[g][0], h0v) + dot4(W[g][1], h1v) +
                     dot4(W[g][2], h2v) + dot4(W[g][3], h3v);
      }
#pragma unroll
      for (int g = 0; g < 4; ++g) acc0[g] = dpp_red(acc0[g]);
    } else if (t > 0) {
      f32x4 v0, v1;  // tid < 256 here
      poll2(h1ring + ((t - 1) & 1) * RING_PAR + tid * 32, (unsigned)(t - 1), v0, v1);
      f32x4 hv; hv.x = v0.x; hv.y = v0.y; hv.z = v0.z; hv.w = v1.x;
      *reinterpret_cast<f32x4*>(&lh1[(t - 1) & 1][lds_idx4(tid)]) = hv;
      lyp[tid] = v1.y;
    }
    __syncthreads();  // S2

    // ---- step3: y[t-1] reduce (wave0), out write ----
    if (t > 0 && wv == 0) {
      float s = (lyp[lane * 4] + lyp[lane * 4 + 1]) + (lyp[lane * 4 + 2] + lyp[lane * 4 + 3]);
      s = dpp_red(s);
      if (lane == 63) {
        float yy = s + bf;
        lys = yy;
        if (blk == 0) out[t - 1] = yy;
      }
    }
    __syncthreads();  // S3

    // ---- step4: L0 finishes h0[t] gates ----
    if (!L1w && lane == 63) {
      if (needy) {
        float yy = lys;
#pragma unroll
        for (int g = 0; g < 4; ++g) acc0[g] += yy * wB[g];
      }
      float h = lstm_h(acc0[0], acc0[1], acc0[2], acc0[3], cc);
      g0h[u] = h;
    }
    __syncthreads();  // S4

    // ---- step5: pub h0[t] ; L1 prefetch ap=bb+wh1*h1[t-1] ; L0 polls h0[t] ----
    if (tid < 2) {
      f32x4 v;
      if (tid == 0) { v.x = g0h[0]; v.y = g0h[1]; v.z = g0h[2]; }
      else { v.x = g0h[3]; v.y = 0.f; v.z = 0.f; }
      v.w = __uint_as_float((unsigned)t);
      st_chunk(h0ring + (t & 1) * RING_PAR + blk * 32 + tid * 16, v);
    }
    if (L1w) {
#pragma unroll
      for (int g = 0; g < 4; ++g) ap[g] = wA[g];
      if (t > 0) {
        const f32x4* hv = reinterpret_cast<const f32x4*>(&lh1[(t - 1) & 1][lane * 20]);
        f32x4 h0v = hv[0], h1v = hv[1], h2v = hv[2], h3v = hv[3];
#pragma unroll
        for (int g = 0; g < 4; ++g) {
          const f32x4* wb = reinterpret_cast<const f32x4*>(
              &wh1_lds[(u * 4 + g) * 1280 + lane * 20]);
          ap[g] += dot4(wb[0], h0v) + dot4(wb[1], h1v) +
                   dot4(wb[2], h2v) + dot4(wb[3], h3v);
        }
      }
    } else {
      const int j = tid - 256;
      f32x4 v0, v1;
      poll2(h0ring + (t & 1) * RING_PAR + j * 32, (unsigned)t, v0, v1);
      f32x4 hv; hv.x = v0.x; hv.y = v0.y; hv.z = v0.z; hv.w = v1.x;
      *reinterpret_cast<f32x4*>(&lh0[lds_idx4(j)]) = hv;
    }
    __syncthreads();  // S5
  }

  // ---- tail: h1[SLEN-1] and out[SLEN-1] ----
  if (L1w) {
    const f32x4* hv = reinterpret_cast<const f32x4*>(&lh0[lane * 20]);
    f32x4 h0v = hv[0], h1v = hv[1], h2v = hv[2], h3v = hv[3];
    float a[4];
#pragma unroll
    for (int g = 0; g < 4; ++g)
      a[g] = ap[g] + dot4(W[g][0], h0v) + dot4(W[g][1], h1v) +
                      dot4(W[g][2], h2v) + dot4(W[g][3], h3v);
#pragma unroll
    for (int g = 0; g < 4; ++g) a[g] = dpp_red(a[g]);
    if (lane == 63) {
      float h = lstm_h(a[0], a[1], a[2], a[3], cc);
      g1h[u] = h; g1yp[u] = wffn * h;
    }
  }
  __syncthreads();
  if (tid < 2) {
    f32x4 v;
    if (tid == 0) { v.x = g1h[0]; v.y = g1h[1]; v.z = g1h[2]; }
    else { v.x = g1h[3]; v.y = (g1yp[0] + g1yp[1]) + (g1yp[2] + g1yp[3]); v.z = 0.f; }
    v.w = __uint_as_float((unsigned)(SLEN - 1));
    st_chunk(h1ring + ((SLEN - 1) & 1) * RING_PAR + blk * 32 + tid * 16, v);
  }
  if (blk == 0) {
    if (tid < 256) {
      f32x4 v0, v1;
      poll2(h1ring + ((SLEN - 1) & 1) * RING_PAR + tid * 32, (unsigned)(SLEN - 1), v0, v1);
      lyp[tid] = v1.y;
    }
    __syncthreads();
    if (wv == 0) {
      float s = (lyp[lane * 4] + lyp[lane * 4 + 1]) + (lyp[lane * 4 + 2] + lyp[lane * 4 + 3]);
      s = dpp_red(s);
      if (lane == 63) out[SLEN - 1] = s + bf;
    }
  }
}

extern "C" void kernel_launch(void* const* d_in, const int* in_sizes, int n_in,
                              void* d_out, int out_size, void* d_ws, size_t ws_size,
                              hipStream_t stream) {
  (void)in_sizes; (void)n_in; (void)out_size; (void)ws_size;
  const float* x      = (const float*)d_in[0];
  const int*   mask   = (const int*)  d_in[1];
  const float* feat   = (const float*)d_in[2];
  const int*   tfp    = (const int*)  d_in[3];
  const float* w_ih0  = (const float*)d_in[4];
  const float* w_hh0  = (const float*)d_in[5];
  const float* b_ih0  = (const float*)d_in[6];
  const float* b_hh0  = (const float*)d_in[7];
  const float* w_ih1  = (const float*)d_in[8];
  const float* w_hh1  = (const float*)d_in[9];
  const float* b_ih1  = (const float*)d_in[10];
  const float* b_hh1  = (const float*)d_in[11];
  const float* w_ffn  = (const float*)d_in[12];
  const float* b_ffn  = (const float*)d_in[13];
  float* out = (float*)d_out;
  char*  ws  = (char*)d_ws;

  // invalidate chunk tags (0xFFFFFFFF never equals a step index)
  hipMemsetAsync(d_ws, 0xFF, (size_t)WS_BYTES, stream);

  lstm_fused<<<dim3(NBLK), dim3(512), 0, stream>>>(
      x, mask, feat, tfp, w_ih0, w_hh0, b_ih0, b_hh0,
      w_ih1, w_hh1, b_ih1, b_hh1, w_ffn, b_ffn, out, ws);
}